// Round 3
// baseline (20903.584 us; speedup 1.0000x reference)
//
#include <hip/hip_runtime.h>
#include <hip/hip_bf16.h>

// LSTM (B=64,T=512,I=512,H=1024,O=1), 2 layers + sigmoid head.
// R3: targeted coherence. No fences, no L2 invalidates.
//  - h exchanged via agent-scope RELAXED atomic u64 load/store (sc0 sc1 =
//    bypass L1/L2, served at the coherence point). Only h pays L3 latency.
//  - x and W use plain cached loads; L2 stays warm across steps.
//  - 128 WGs x 512 thr; WG owns 8 hidden units (2 gate tiles x 4 units).
//    8 waves = 4 batch tiles x 2 unit tiles.
//  - hh A-operand: issue all 64 bypass loads into registers, then MFMA chain
//    (one exposed L3 round trip instead of 32).
//  - 2-level arrival (4 groups x 32), relaxed atomics, monotonic counters.

namespace {

constexpr int B_ = 64, T_ = 512, I_ = 512, H_ = 1024;
constexpr int NWG = 128, NTHR = 512;

typedef __attribute__((ext_vector_type(8))) short short8;
typedef __attribute__((ext_vector_type(4))) float f32x4;

__device__ __forceinline__ float sigm(float x)  { return 1.f / (1.f + __expf(-x)); }
__device__ __forceinline__ float tanhx(float x) { return 2.f / (1.f + __expf(-2.f * x)) - 1.f; }

__device__ __forceinline__ unsigned f2bf(float f) {
  unsigned u = __float_as_uint(f);
  unsigned rnd = 0x7FFFu + ((u >> 16) & 1u);
  return (u + rnd) >> 16;   // low 16 bits valid
}
__device__ __forceinline__ float bf2f(unsigned short s) {
  return __uint_as_float(((unsigned)s) << 16);
}

__device__ __forceinline__ short8 pack2(unsigned long long a, unsigned long long b) {
  union { unsigned long long q[2]; short8 v; } u;
  u.q[0] = a; u.q[1] = b;
  return u.v;
}

__global__ void cvt_bf16_k(const float* __restrict__ src, unsigned short* __restrict__ dst, int n4) {
  int i = blockIdx.x * 256 + threadIdx.x;
  if (i >= n4) return;
  float4 v = reinterpret_cast<const float4*>(src)[i];
  ushort4 o;
  o.x = (unsigned short)f2bf(v.x); o.y = (unsigned short)f2bf(v.y);
  o.z = (unsigned short)f2bf(v.z); o.w = (unsigned short)f2bf(v.w);
  reinterpret_cast<ushort4*>(dst)[i] = o;
}

__global__ void zero_init_k(unsigned short* __restrict__ h1, unsigned short* __restrict__ h2,
                            unsigned* __restrict__ bar) {
  int i = blockIdx.x * 256 + threadIdx.x;
  if (i < B_ * H_) h1[i] = 0;           // h1 slab 0 (t=-1 state)
  if (i < 2 * B_ * H_) h2[i] = 0;       // h2 ping-pong slabs
  if (i < 1024) bar[i] = 0;             // both layers' barrier counters
}

// Barrier region per layer: glob at [0]; group g (4 groups of 32 WGs) at
// [64 + 32*g]. Monotonic counters, zeroed per launch.
// hout: [slabs][B][H] bf16; read slab t&wr_mask, write slab (t+1)&wr_mask.
template<int K_IN>
__global__ __launch_bounds__(NTHR, 2) void lstm_layer(
    const unsigned short* __restrict__ in, size_t in_stride_t, size_t in_stride_b,
    const unsigned short* __restrict__ w_in,   // [4H][K_IN] bf16
    const unsigned short* __restrict__ w_hh,   // [4H][H] bf16
    const float* __restrict__ b_ih, const float* __restrict__ b_hh,
    unsigned short* __restrict__ hout, int wr_mask,
    unsigned* __restrict__ bars)
{
  __shared__ unsigned short s_win[32 * K_IN];
  __shared__ unsigned short s_whh[32 * H_];

  const int tid  = threadIdx.x;
  const int wg   = blockIdx.x;      // 0..127
  const int wave = tid >> 6;        // 0..7
  const int lane = tid & 63;
  const int bt   = wave >> 1;       // batch tile 0..3
  const int nt   = wave & 1;        // unit tile 0..1
  const int j0   = wg * 8;          // first hidden unit owned by this WG
  const int n    = lane & 15;       // column within this wave's 16x16 tile

  unsigned* glob = bars;
  unsigned* grp  = bars + 64 + (wg >> 5) * 32;

  // ---- stage W slices into LDS, XOR swizzle (shorts: k ^= (r&7)<<3) ----
  // slice row r in [0,32): nt_r=r>>4, n_r=r&15 -> gate g=(r&15)>>2, unit u=r&3
  // global gate row: g*H + j0 + nt_r*4 + u
  constexpr int CH_IN = K_IN / 8;
  for (int c = tid; c < 32 * CH_IN; c += NTHR) {
    int r = c / CH_IN;
    int kc = (c % CH_IN) * 8;
    int grow = ((r & 15) >> 2) * H_ + j0 + (r >> 4) * 4 + (r & 3);
    *reinterpret_cast<short8*>(&s_win[r * K_IN + (kc ^ ((r & 7) << 3))]) =
        *reinterpret_cast<const short8*>(&w_in[(size_t)grow * K_IN + kc]);
  }
  constexpr int CH_HH = H_ / 8;
  for (int c = tid; c < 32 * CH_HH; c += NTHR) {
    int r = c / CH_HH;
    int kc = (c % CH_HH) * 8;
    int grow = ((r & 15) >> 2) * H_ + j0 + (r >> 4) * 4 + (r & 3);
    *reinterpret_cast<short8*>(&s_whh[r * H_ + (kc ^ ((r & 7) << 3))]) =
        *reinterpret_cast<const short8*>(&w_hh[(size_t)grow * H_ + kc]);
  }
  const int grow_n = (n >> 2) * H_ + j0 + nt * 4 + (n & 3);
  const float bias_n = b_ih[grow_n] + b_hh[grow_n];
  __syncthreads();

  // ---- per-lane MFMA addressing ----
  const int k0    = (lane >> 4) * 8;      // k offset within 32-wide K tile
  const int arow  = bt * 16 + n;          // batch row (A fragment)
  const int rrow  = nt * 16 + n;          // W slice row (B fragment)
  const int swz_n = (n & 7) << 3;
  // ---- elementwise identity: thread -> (batch, unit) ----
  const int eb = bt * 16 + (lane >> 2);   // batch 0..63
  const int eu = lane & 3;                // unit within tile
  const int ub = j0 + nt * 4;             // unit base for this wave
  float cst = 0.f;

  const unsigned short* a_in_base = in + (size_t)arow * in_stride_b + k0;
  const unsigned long long* hq_base =
      (const unsigned long long*)hout + ((size_t)arow * H_ + k0) / 4;

  for (int t = 0; t < T_; ++t) {
    f32x4 acc = {0.f, 0.f, 0.f, 0.f};

    // ---- A: input GEMM (cached loads, no barrier dependence) ----
    const unsigned short* a_in = a_in_base + (size_t)t * in_stride_t;
    #pragma unroll
    for (int kk = 0; kk < K_IN / 32; ++kk) {
      short8 av = *reinterpret_cast<const short8*>(a_in + kk * 32);
      short8 bv = *reinterpret_cast<const short8*>(&s_win[rrow * K_IN + ((k0 + kk * 32) ^ swz_n)]);
      acc = __builtin_amdgcn_mfma_f32_16x16x32_bf16(av, bv, acc, 0, 0, 0);
    }

    // ---- B: wait for h[t] ----
    if (t > 0) {
      if (tid == 0) {
        const unsigned tgt = (unsigned)t * 4u;
        while (__hip_atomic_load(glob, __ATOMIC_RELAXED, __HIP_MEMORY_SCOPE_AGENT) < tgt)
          __builtin_amdgcn_s_sleep(1);
      }
      __syncthreads();
    }

    // ---- C: recurrent GEMM. Bypass loads (sc0 sc1) of h, all issued first ----
    const unsigned long long* hq = hq_base + (size_t)(t & wr_mask) * (B_ * H_ / 4);
    unsigned long long qa[H_ / 32], qb[H_ / 32];
    #pragma unroll
    for (int kk = 0; kk < H_ / 32; ++kk) {
      qa[kk] = __hip_atomic_load(hq + kk * 8,     __ATOMIC_RELAXED, __HIP_MEMORY_SCOPE_AGENT);
      qb[kk] = __hip_atomic_load(hq + kk * 8 + 1, __ATOMIC_RELAXED, __HIP_MEMORY_SCOPE_AGENT);
    }
    #pragma unroll
    for (int kk = 0; kk < H_ / 32; ++kk) {
      short8 bv = *reinterpret_cast<const short8*>(&s_whh[rrow * H_ + ((k0 + kk * 32) ^ swz_n)]);
      acc = __builtin_amdgcn_mfma_f32_16x16x32_bf16(pack2(qa[kk], qb[kk]), bv, acc, 0, 0, 0);
    }
    acc[0] += bias_n; acc[1] += bias_n; acc[2] += bias_n; acc[3] += bias_n;

    // ---- D: redistribute gates within the wave, elementwise ----
    // lane holds P[m=(lane>>4)*4+r][n=lane&15]; thread (eb_local=lane>>2,
    // eu=lane&3) needs P[eb_local][g*4+eu] for g=0..3.
    const int rsel  = (lane >> 2) & 3;
    const int sbase = (lane & 48) | (lane & 3);
    float pg[4];
    #pragma unroll
    for (int g = 0; g < 4; ++g) {
      int src = sbase | (g << 2);
      float t0 = __shfl(acc[0], src, 64);
      float t1 = __shfl(acc[1], src, 64);
      float t2 = __shfl(acc[2], src, 64);
      float t3 = __shfl(acc[3], src, 64);
      pg[g] = (rsel == 0) ? t0 : (rsel == 1) ? t1 : (rsel == 2) ? t2 : t3;
    }
    float gi = sigm(pg[0]);
    float gf = sigm(pg[1]);
    float gg = tanhx(pg[2]);
    float go = sigm(pg[3]);
    cst = gf * cst + gi * gg;
    float hv = go * tanhx(cst);

    // pack this wave's 4 units for batch eb into one u64, bypass store
    unsigned hv16 = f2bf(hv) & 0xFFFFu;
    const int lb = lane & ~3;
    unsigned v1 = __shfl(hv16, lb | 1, 64);
    unsigned v2 = __shfl(hv16, lb | 2, 64);
    unsigned v3 = __shfl(hv16, lb | 3, 64);
    if (eu == 0) {
      unsigned long long q = (unsigned long long)(hv16 | (v1 << 16)) |
                             ((unsigned long long)(v2 | (v3 << 16)) << 32);
      unsigned long long* dst = (unsigned long long*)
          (hout + (size_t)((t + 1) & wr_mask) * (B_ * H_) + (size_t)eb * H_ + ub);
      __hip_atomic_store(dst, q, __ATOMIC_RELAXED, __HIP_MEMORY_SCOPE_AGENT);
    }

    // ---- E: arrive (syncthreads drains vmcnt -> stores are at L3) ----
    __syncthreads();
    if (tid == 0) {
      unsigned old = __hip_atomic_fetch_add(grp, 1u, __ATOMIC_RELAXED, __HIP_MEMORY_SCOPE_AGENT);
      if (old == (unsigned)t * 32u + 31u)
        __hip_atomic_fetch_add(glob, 1u, __ATOMIC_RELAXED, __HIP_MEMORY_SCOPE_AGENT);
    }
  }
}

__global__ void out_head(const unsigned short* __restrict__ h2,
                         const float* __restrict__ W_out,
                         const float* __restrict__ b_out,
                         float* __restrict__ out) {
  int b = blockIdx.x;      // 64
  int lane = threadIdx.x;  // 64 (one wave)
  float s = 0.f;
  for (int k = lane; k < H_; k += 64)
    s += bf2f(h2[(size_t)b * H_ + k]) * W_out[k];
  #pragma unroll
  for (int off = 32; off; off >>= 1) s += __shfl_down(s, off, 64);
  if (lane == 0) out[b] = sigm(s + b_out[0]);
}

} // namespace

extern "C" void kernel_launch(void* const* d_in, const int* in_sizes, int n_in,
                              void* d_out, int out_size, void* d_ws, size_t ws_size,
                              hipStream_t stream) {
  const float* x    = (const float*)d_in[0];
  const float* Wih0 = (const float*)d_in[1];
  const float* Whh0 = (const float*)d_in[2];
  const float* bih0 = (const float*)d_in[3];
  const float* bhh0 = (const float*)d_in[4];
  const float* Wih1 = (const float*)d_in[5];
  const float* Whh1 = (const float*)d_in[6];
  const float* bih1 = (const float*)d_in[7];
  const float* bhh1 = (const float*)d_in[8];
  const float* Wout = (const float*)d_in[9];
  const float* bout = (const float*)d_in[10];
  float* out = (float*)d_out;

  char* ws = (char*)d_ws;
  size_t off = 0;
  auto alloc = [&](size_t bytes) -> char* {
    char* p = ws + off;
    off += (bytes + 255) & ~(size_t)255;
    return p;
  };
  unsigned* bar        = (unsigned*)alloc(4096);  // 2 layers x 512 u32
  unsigned short* xb   = (unsigned short*)alloc((size_t)B_ * T_ * I_ * 2);
  unsigned short* wih0 = (unsigned short*)alloc((size_t)4 * H_ * I_ * 2);
  unsigned short* whh0 = (unsigned short*)alloc((size_t)4 * H_ * H_ * 2);
  unsigned short* wih1 = (unsigned short*)alloc((size_t)4 * H_ * H_ * 2);
  unsigned short* whh1 = (unsigned short*)alloc((size_t)4 * H_ * H_ * 2);
  unsigned short* h1   = (unsigned short*)alloc((size_t)(T_ + 1) * B_ * H_ * 2);
  unsigned short* h2   = (unsigned short*)alloc((size_t)2 * B_ * H_ * 2);

  auto cvt = [&](const float* s, unsigned short* d, int nelem) {
    int n4 = nelem / 4;
    cvt_bf16_k<<<(n4 + 255) / 256, 256, 0, stream>>>(s, d, n4);
  };
  cvt(x,    xb,   B_ * T_ * I_);
  cvt(Wih0, wih0, 4 * H_ * I_);
  cvt(Whh0, whh0, 4 * H_ * H_);
  cvt(Wih1, wih1, 4 * H_ * H_);
  cvt(Whh1, whh1, 4 * H_ * H_);
  zero_init_k<<<(2 * B_ * H_ + 255) / 256, 256, 0, stream>>>(h1, h2, bar);

  // layer 0: input x [B][T][I] (stride_t = I, stride_b = T*I), full h1 record
  lstm_layer<I_><<<NWG, NTHR, 0, stream>>>(
      xb, (size_t)I_, (size_t)T_ * I_,
      wih0, whh0, bih0, bhh0, h1, 1023, bar);

  // layer 1: input h1 slabs 1..512 ([t][b][k]: stride_t = B*H, stride_b = H),
  // h2 ping-pong (final h at slab 0 since T even)
  lstm_layer<H_><<<NWG, NTHR, 0, stream>>>(
      h1 + B_ * H_, (size_t)B_ * H_, (size_t)H_,
      wih1, whh1, bih1, bhh1, h2, 1, bar + 512);

  out_head<<<B_, 64, 0, stream>>>(h2, Wout, bout, out);
}

// Round 4
// 15401.305 us; speedup vs baseline: 1.3573x; 1.3573x over previous
//
#include <hip/hip_runtime.h>
#include <hip/hip_bf16.h>

// LSTM (B=64,T=512,I=512,H=1024,O=1), 2 layers + sigmoid head.
// R4: register-resident weights + K-split waves + overlapped input GEMM.
//  - 256 WGs x 512 thr. WG owns 4 hidden units (16 gate rows). 8 waves =
//    4 batch tiles x 2 K-halves. W_in/W_hh fragments held in VGPRs (no LDS W).
//  - h exchanged via agent-scope RELAXED atomic u64 stores/loads (L3-direct,
//    coherent, no fences, no L2 invalidates). Per wave only 32 u64 of h are
//    staged -> fits in registers (R3 spilled 64 u64 -> scratch, the regression).
//  - Partial accs (K-halves) combined via small padded LDS buffer.
//  - Input GEMM for step t+1 runs after the h store, hiding the
//    arrive->release round trip.
//  - Release: wave 0 polls the 8 group arrival counters (lanes 0-7 + __all),
//    then sets an LDS flag for the other waves.

namespace {

constexpr int B_ = 64, T_ = 512, I_ = 512, H_ = 1024;
constexpr int NWG = 256, NTHR = 512;

typedef __attribute__((ext_vector_type(8))) short short8;
typedef __attribute__((ext_vector_type(4))) float f32x4;

__device__ __forceinline__ float sigm(float x)  { return 1.f / (1.f + __expf(-x)); }
__device__ __forceinline__ float tanhx(float x) { return 2.f / (1.f + __expf(-2.f * x)) - 1.f; }

__device__ __forceinline__ unsigned f2bf(float f) {
  unsigned u = __float_as_uint(f);
  unsigned rnd = 0x7FFFu + ((u >> 16) & 1u);
  return (u + rnd) >> 16;   // low 16 bits valid
}
__device__ __forceinline__ float bf2f(unsigned short s) {
  return __uint_as_float(((unsigned)s) << 16);
}

__device__ __forceinline__ short8 pack2(unsigned long long a, unsigned long long b) {
  union { unsigned long long q[2]; short8 v; } u;
  u.q[0] = a; u.q[1] = b;
  return u.v;
}

__global__ void cvt_bf16_k(const float* __restrict__ src, unsigned short* __restrict__ dst, int n4) {
  int i = blockIdx.x * 256 + threadIdx.x;
  if (i >= n4) return;
  float4 v = reinterpret_cast<const float4*>(src)[i];
  ushort4 o;
  o.x = (unsigned short)f2bf(v.x); o.y = (unsigned short)f2bf(v.y);
  o.z = (unsigned short)f2bf(v.z); o.w = (unsigned short)f2bf(v.w);
  reinterpret_cast<ushort4*>(dst)[i] = o;
}

__global__ void zero_init_k(unsigned short* __restrict__ h1, unsigned short* __restrict__ h2,
                            unsigned* __restrict__ bar) {
  int i = blockIdx.x * 256 + threadIdx.x;
  if (i < B_ * H_) h1[i] = 0;           // h1 slab 0 (t=-1 state)
  if (i < 2 * B_ * H_) h2[i] = 0;       // h2 ping-pong slabs
  if (i < 1024) bar[i] = 0;             // both layers' barrier counters
}

// bars per layer: group g (8 groups of 32 WGs) counter at bars[g*32]
// (separate 128B lines). Monotonic: after all arrivals of iteration t,
// each counter == 32*(t+1). Release(t) condition: all counters >= 32*t.
// hout: [slabs][B][H] bf16; read slab t&wr_mask, write slab (t+1)&wr_mask.
template<int K_IN>
__global__ __launch_bounds__(NTHR, 2) void lstm_layer(
    const unsigned short* __restrict__ in, size_t in_stride_t, size_t in_stride_b,
    const unsigned short* __restrict__ w_in,   // [4H][K_IN] bf16
    const unsigned short* __restrict__ w_hh,   // [4H][H] bf16
    const float* __restrict__ b_ih, const float* __restrict__ b_hh,
    unsigned short* __restrict__ hout, int wr_mask,
    unsigned* __restrict__ bars)
{
  constexpr int KT_IN = K_IN / 64;   // 32-wide k-tiles per K-half (L0:8, L1:16)
  constexpr int KT_HH = H_ / 64;     // 16

  __shared__ float gxbuf[4][16][17]; // padded: +1 breaks bank aliasing
  __shared__ int rel_flag;

  const int tid  = threadIdx.x;
  const int wg   = blockIdx.x;      // 0..255
  const int wave = tid >> 6;        // 0..7
  const int lane = tid & 63;
  const int bt   = wave & 3;        // batch tile
  const int kh   = wave >> 2;       // K-half
  const int j0   = wg * 4;          // first hidden unit owned by this WG
  const int n    = lane & 15;       // gate-row within tile
  const int k0   = (lane >> 4) * 8; // k offset within 32-wide K tile
  const int grow_n = (n >> 2) * H_ + j0 + (n & 3);
  const int arow = bt * 16 + n;     // batch row (A fragment)

  if (tid == 0) rel_flag = 0;

  // ---- W fragments into registers (one-time) ----
  short8 bin[KT_IN], bhh[KT_HH];
  #pragma unroll
  for (int kk = 0; kk < KT_IN; ++kk)
    bin[kk] = *reinterpret_cast<const short8*>(
        &w_in[(size_t)grow_n * K_IN + kh * (K_IN / 2) + kk * 32 + k0]);
  #pragma unroll
  for (int kk = 0; kk < KT_HH; ++kk)
    bhh[kk] = *reinterpret_cast<const short8*>(
        &w_hh[(size_t)grow_n * H_ + kh * (H_ / 2) + kk * 32 + k0]);
  const float bias_n = b_ih[grow_n] + b_hh[grow_n];

  // elementwise identity (kh==0 waves): thread -> (batch, unit)
  const int eb = bt * 16 + (lane >> 2);
  const int eu = lane & 3;
  float cst = 0.f;

  const unsigned short* a_in_base = in + (size_t)arow * in_stride_b + kh * (K_IN / 2) + k0;
  const size_t h_lane_off = ((size_t)arow * H_ + (size_t)kh * (H_ / 2) + k0) >> 2; // u64 units

  __syncthreads();  // rel_flag visible

  // prologue: in-partial for t=0
  f32x4 acc = {0.f, 0.f, 0.f, 0.f};
  #pragma unroll
  for (int kk = 0; kk < KT_IN; ++kk) {
    short8 av = *reinterpret_cast<const short8*>(a_in_base + kk * 32);
    acc = __builtin_amdgcn_mfma_f32_16x16x32_bf16(av, bin[kk], acc, 0, 0, 0);
  }

  for (int t = 0; t < T_; ++t) {
    if (t > 0) {
      // ---- release wait for h[t] ----
      if (wave == 0) {
        const unsigned tgt = (unsigned)t * 32u;
        for (;;) {
          unsigned v = 0xFFFFFFFFu;
          if (lane < 8)
            v = __hip_atomic_load(bars + lane * 32, __ATOMIC_RELAXED, __HIP_MEMORY_SCOPE_AGENT);
          if (__all((int)(lane >= 8 || v >= tgt))) break;
          __builtin_amdgcn_s_sleep(1);
        }
        if (lane == 0)
          __hip_atomic_store(&rel_flag, t, __ATOMIC_RELEASE, __HIP_MEMORY_SCOPE_WORKGROUP);
      } else {
        while (__hip_atomic_load(&rel_flag, __ATOMIC_ACQUIRE, __HIP_MEMORY_SCOPE_WORKGROUP) < t)
          __builtin_amdgcn_s_sleep(1);
      }

      // ---- recurrent GEMM, K-half: 32 u64 bypass loads then MFMA chain ----
      const unsigned long long* hq = reinterpret_cast<const unsigned long long*>(hout)
          + (size_t)(t & wr_mask) * (B_ * H_ / 4) + h_lane_off;
      unsigned long long q[2 * KT_HH];
      #pragma unroll
      for (int kk = 0; kk < KT_HH; ++kk) {
        q[2 * kk]     = __hip_atomic_load(hq + kk * 8,     __ATOMIC_RELAXED, __HIP_MEMORY_SCOPE_AGENT);
        q[2 * kk + 1] = __hip_atomic_load(hq + kk * 8 + 1, __ATOMIC_RELAXED, __HIP_MEMORY_SCOPE_AGENT);
      }
      #pragma unroll
      for (int kk = 0; kk < KT_HH; ++kk)
        acc = __builtin_amdgcn_mfma_f32_16x16x32_bf16(pack2(q[2 * kk], q[2 * kk + 1]),
                                                      bhh[kk], acc, 0, 0, 0);
    }

    // ---- combine K-halves via LDS ----
    if (kh == 1) {
      #pragma unroll
      for (int r = 0; r < 4; ++r)
        gxbuf[bt][(lane >> 4) * 4 + r][n] = acc[r];
    }
    __syncthreads();   // kh1 partials visible

    if (kh == 0) {
      #pragma unroll
      for (int r = 0; r < 4; ++r)
        acc[r] += gxbuf[bt][(lane >> 4) * 4 + r][n] + bias_n;

      // redistribute gates within wave: thread (eb_local=lane>>2, eu=lane&3)
      // needs P[eb_local][g*4+eu] from lane (lane&48)|(g<<2)|(lane&3), reg (lane>>2)&3
      const int rsel  = (lane >> 2) & 3;
      const int sbase = (lane & 48) | (lane & 3);
      float pg[4];
      #pragma unroll
      for (int g = 0; g < 4; ++g) {
        int src = sbase | (g << 2);
        float t0 = __shfl(acc[0], src, 64);
        float t1 = __shfl(acc[1], src, 64);
        float t2 = __shfl(acc[2], src, 64);
        float t3 = __shfl(acc[3], src, 64);
        pg[g] = (rsel == 0) ? t0 : (rsel == 1) ? t1 : (rsel == 2) ? t2 : t3;
      }
      float gi = sigm(pg[0]);
      float gf = sigm(pg[1]);
      float gg = tanhx(pg[2]);
      float go = sigm(pg[3]);
      cst = gf * cst + gi * gg;
      float hv = go * tanhx(cst);

      // pack 4 units for batch eb into one u64, bypass store
      unsigned hv16 = f2bf(hv) & 0xFFFFu;
      const int lb = lane & ~3;
      unsigned v1 = __shfl(hv16, lb | 1, 64);
      unsigned v2 = __shfl(hv16, lb | 2, 64);
      unsigned v3 = __shfl(hv16, lb | 3, 64);
      if (eu == 0) {
        unsigned long long qv = (unsigned long long)(hv16 | (v1 << 16)) |
                                ((unsigned long long)(v2 | (v3 << 16)) << 32);
        unsigned long long* dst = (unsigned long long*)
            (hout + (size_t)((t + 1) & wr_mask) * (B_ * H_) + (size_t)eb * H_ + j0);
        __hip_atomic_store(dst, qv, __ATOMIC_RELAXED, __HIP_MEMORY_SCOPE_AGENT);
      }
    }

    // ---- input GEMM for t+1 (hides the arrive->release round trip) ----
    const int tn = (t + 1 < T_) ? t + 1 : t;
    f32x4 nacc = {0.f, 0.f, 0.f, 0.f};
    const unsigned short* a_in = a_in_base + (size_t)tn * in_stride_t;
    #pragma unroll
    for (int kk = 0; kk < KT_IN; ++kk) {
      short8 av = *reinterpret_cast<const short8*>(a_in + kk * 32);
      nacc = __builtin_amdgcn_mfma_f32_16x16x32_bf16(av, bin[kk], nacc, 0, 0, 0);
    }

    // ---- arrive: barrier drains each wave's stores (vmcnt0) first ----
    __syncthreads();
    if (tid == 0)
      __hip_atomic_fetch_add(bars + (wg >> 5) * 32, 1u, __ATOMIC_RELAXED, __HIP_MEMORY_SCOPE_AGENT);

    acc = nacc;
  }
}

__global__ void out_head(const unsigned short* __restrict__ h2,
                         const float* __restrict__ W_out,
                         const float* __restrict__ b_out,
                         float* __restrict__ out) {
  int b = blockIdx.x;      // 64
  int lane = threadIdx.x;  // 64 (one wave)
  float s = 0.f;
  for (int k = lane; k < H_; k += 64)
    s += bf2f(h2[(size_t)b * H_ + k]) * W_out[k];
  #pragma unroll
  for (int off = 32; off; off >>= 1) s += __shfl_down(s, off, 64);
  if (lane == 0) out[b] = sigm(s + b_out[0]);
}

} // namespace

extern "C" void kernel_launch(void* const* d_in, const int* in_sizes, int n_in,
                              void* d_out, int out_size, void* d_ws, size_t ws_size,
                              hipStream_t stream) {
  const float* x    = (const float*)d_in[0];
  const float* Wih0 = (const float*)d_in[1];
  const float* Whh0 = (const float*)d_in[2];
  const float* bih0 = (const float*)d_in[3];
  const float* bhh0 = (const float*)d_in[4];
  const float* Wih1 = (const float*)d_in[5];
  const float* Whh1 = (const float*)d_in[6];
  const float* bih1 = (const float*)d_in[7];
  const float* bhh1 = (const float*)d_in[8];
  const float* Wout = (const float*)d_in[9];
  const float* bout = (const float*)d_in[10];
  float* out = (float*)d_out;

  char* ws = (char*)d_ws;
  size_t off = 0;
  auto alloc = [&](size_t bytes) -> char* {
    char* p = ws + off;
    off += (bytes + 255) & ~(size_t)255;
    return p;
  };
  unsigned* bar        = (unsigned*)alloc(4096);  // 2 layers x 256 u32 (+slack)
  unsigned short* xb   = (unsigned short*)alloc((size_t)B_ * T_ * I_ * 2);
  unsigned short* wih0 = (unsigned short*)alloc((size_t)4 * H_ * I_ * 2);
  unsigned short* whh0 = (unsigned short*)alloc((size_t)4 * H_ * H_ * 2);
  unsigned short* wih1 = (unsigned short*)alloc((size_t)4 * H_ * H_ * 2);
  unsigned short* whh1 = (unsigned short*)alloc((size_t)4 * H_ * H_ * 2);
  unsigned short* h1   = (unsigned short*)alloc((size_t)(T_ + 1) * B_ * H_ * 2);
  unsigned short* h2   = (unsigned short*)alloc((size_t)2 * B_ * H_ * 2);

  auto cvt = [&](const float* s, unsigned short* d, int nelem) {
    int n4 = nelem / 4;
    cvt_bf16_k<<<(n4 + 255) / 256, 256, 0, stream>>>(s, d, n4);
  };
  cvt(x,    xb,   B_ * T_ * I_);
  cvt(Wih0, wih0, 4 * H_ * I_);
  cvt(Whh0, whh0, 4 * H_ * H_);
  cvt(Wih1, wih1, 4 * H_ * H_);
  cvt(Whh1, whh1, 4 * H_ * H_);
  zero_init_k<<<(2 * B_ * H_ + 255) / 256, 256, 0, stream>>>(h1, h2, bar);

  // layer 0: input x [B][T][I] (stride_t = I, stride_b = T*I), full h1 record
  lstm_layer<I_><<<NWG, NTHR, 0, stream>>>(
      xb, (size_t)I_, (size_t)T_ * I_,
      wih0, whh0, bih0, bhh0, h1, 1023, bar);

  // layer 1: input h1 slabs 1..512 ([t][b][k]: stride_t = B*H, stride_b = H),
  // h2 ping-pong (final h at slab 0 since T even)
  lstm_layer<H_><<<NWG, NTHR, 0, stream>>>(
      h1 + B_ * H_, (size_t)B_ * H_, (size_t)H_,
      wih1, whh1, bih1, bhh1, h2, 1, bar + 512);

  out_head<<<B_, 64, 0, stream>>>(h2, Wout, bout, out);
}